// Round 1
// baseline (1218.931 us; speedup 1.0000x reference)
//
#include <hip/hip_runtime.h>
#include <math.h>

#define R 10
#define C 6
#define HID 128
#define HEADS 4
#define NL 3
#define KO (HEADS*HID)   // 512
#define TOK (R*HID)      // 1280
#define LN_EPS 1e-5f
#define NEG_SLOPE 0.2f
#define MAXE 64
#define MAXDEG 16

__device__ __forceinline__ float gelu_exact(float v) {
    return 0.5f * v * (1.0f + erff(v * 0.70710678118654752440f));
}

__global__ __launch_bounds__(256, 4) void fused_gnn_kernel(
    const float* __restrict__ x,      // (BT, R*C)
    const float* __restrict__ Wenc,   // (R, C, HID)
    const float* __restrict__ benc,   // (R, HID)
    const float* __restrict__ gamma_, // (R, HID)
    const float* __restrict__ beta_,  // (R, HID)
    const float* __restrict__ Wg,     // (NL, HID, KO)
    const float* __restrict__ asrc,   // (NL, HEADS, HID)
    const float* __restrict__ adst,   // (NL, HEADS, HID)
    const float* __restrict__ bg,     // (NL, HID)
    const int* __restrict__ srce,     // (E,)
    const int* __restrict__ dste,     // (E,)
    float* __restrict__ gf_out,       // (BT, TOK)
    float* __restrict__ rf_out,       // (BT, TOK)
    int E)
{
    __shared__ __align__(16) float s_nf[R*HID];   // node features (residual stream)
    __shared__ __align__(16) float s_xp[R*KO];    // projected features; reused as h in encoder
    __shared__ float s_xr[R*C];
    __shared__ float s_als[R*HEADS];
    __shared__ float s_ald[R*HEADS];
    __shared__ float s_alpha[MAXE*HEADS];
    __shared__ float s_mu[R], s_rs[R];
    __shared__ int s_src[MAXE], s_dst[MAXE];
    __shared__ int s_eid[R*MAXDEG];
    __shared__ int s_deg[R];

    const int t = threadIdx.x;
    const int tok = blockIdx.x;
    const int wave = t >> 6;
    const int lane = t & 63;

    // ---- stage token input + edge list ----
    if (t < R*C) s_xr[t] = x[(size_t)tok*(R*C) + t];
    if (t < E && t < MAXE) { s_src[t] = srce[t]; s_dst[t] = dste[t]; }
    __syncthreads();
    // CSR by destination, one thread per node (E=36, trivial)
    if (t < R) {
        int d = 0;
        for (int e = 0; e < E && e < MAXE; ++e)
            if (s_dst[e] == t && d < MAXDEG) s_eid[t*MAXDEG + (d++)] = e;
        s_deg[t] = d;
    }

    // ---- encoder: h = x @ Wenc + benc (into s_xp scratch) ----
    for (int i = t; i < R*HID; i += 256) {
        int r = i >> 7;
        float acc = benc[i];
        #pragma unroll
        for (int c = 0; c < C; ++c)
            acc += s_xr[r*C + c] * Wenc[(r*C + c)*HID + (i & (HID-1))];
        s_xp[i] = acc;
    }
    __syncthreads();

    // ---- LayerNorm stats: one wave per row (2 elems/lane + shuffle reduce) ----
    for (int r = wave; r < R; r += 4) {
        float v0 = s_xp[r*HID + lane];
        float v1 = s_xp[r*HID + lane + 64];
        float sum = v0 + v1;
        float sq  = v0*v0 + v1*v1;
        #pragma unroll
        for (int off = 32; off > 0; off >>= 1) {
            sum += __shfl_down(sum, off);
            sq  += __shfl_down(sq,  off);
        }
        if (lane == 0) {
            float mu  = sum * (1.0f/HID);
            float var = sq * (1.0f/HID) - mu*mu;
            s_mu[r] = mu;
            s_rs[r] = rsqrtf(var + LN_EPS);
        }
    }
    __syncthreads();

    // ---- normalize + affine + gelu -> region_feats (second output) + s_nf ----
    for (int i = t; i < R*HID; i += 256) {
        int r = i >> 7;
        float v = (s_xp[i] - s_mu[r]) * s_rs[r] * gamma_[i] + beta_[i];
        v = gelu_exact(v);
        s_nf[i] = v;
        rf_out[(size_t)tok*TOK + i] = v;
    }
    __syncthreads();

    // ---- 3 GAT layers ----
    for (int l = 0; l < NL; ++l) {
        const float* __restrict__ W = Wg + (size_t)l*HID*KO;

        // GEMM: xp[r][ko] for ko in {t, t+256}; nf broadcast from LDS (float4)
        float acc0[R], acc1[R];
        #pragma unroll
        for (int r = 0; r < R; ++r) { acc0[r] = 0.f; acc1[r] = 0.f; }
        for (int c = 0; c < HID; c += 4) {
            float w00 = W[(c+0)*KO + t];
            float w01 = W[(c+1)*KO + t];
            float w02 = W[(c+2)*KO + t];
            float w03 = W[(c+3)*KO + t];
            float w10 = W[(c+0)*KO + t + 256];
            float w11 = W[(c+1)*KO + t + 256];
            float w12 = W[(c+2)*KO + t + 256];
            float w13 = W[(c+3)*KO + t + 256];
            #pragma unroll
            for (int r = 0; r < R; ++r) {
                float4 nv = *(const float4*)&s_nf[r*HID + c];
                acc0[r] = fmaf(nv.x, w00, acc0[r]);
                acc0[r] = fmaf(nv.y, w01, acc0[r]);
                acc0[r] = fmaf(nv.z, w02, acc0[r]);
                acc0[r] = fmaf(nv.w, w03, acc0[r]);
                acc1[r] = fmaf(nv.x, w10, acc1[r]);
                acc1[r] = fmaf(nv.y, w11, acc1[r]);
                acc1[r] = fmaf(nv.z, w12, acc1[r]);
                acc1[r] = fmaf(nv.w, w13, acc1[r]);
            }
        }
        #pragma unroll
        for (int r = 0; r < R; ++r) {
            s_xp[r*KO + t]       = acc0[r];
            s_xp[r*KO + t + 256] = acc1[r];
        }
        __syncthreads();

        // attention logits: 80 length-128 dots, one per wave-iteration
        for (int id = wave; id < R*HEADS*2; id += 4) {
            int r   = id >> 3;
            int h   = (id >> 1) & 3;
            int isd = id & 1;
            const float* av = (isd ? adst : asrc) + ((size_t)l*HEADS + h)*HID;
            float v = s_xp[r*KO + h*HID + lane]      * av[lane]
                    + s_xp[r*KO + h*HID + lane + 64] * av[lane + 64];
            #pragma unroll
            for (int off = 32; off > 0; off >>= 1) v += __shfl_down(v, off);
            if (lane == 0) {
                if (isd) s_ald[r*HEADS + h] = v;
                else     s_als[r*HEADS + h] = v;
            }
        }
        __syncthreads();

        // segment softmax per (dst node, head): 40 active threads
        if (t < R*HEADS) {
            int r = t >> 2;
            int h = t & 3;
            int d = s_deg[r];
            float ald = s_ald[r*HEADS + h];
            float m = -1e30f;
            for (int k = 0; k < d; ++k) {
                int e = s_eid[r*MAXDEG + k];
                float val = s_als[s_src[e]*HEADS + h] + ald;
                val = (val > 0.f) ? val : NEG_SLOPE*val;
                m = fmaxf(m, val);
            }
            float ssum = 0.f;
            for (int k = 0; k < d; ++k) {
                int e = s_eid[r*MAXDEG + k];
                float val = s_als[s_src[e]*HEADS + h] + ald;
                val = (val > 0.f) ? val : NEG_SLOPE*val;
                ssum += expf(val - m);
            }
            float inv = 1.0f / ssum;
            for (int k = 0; k < d; ++k) {
                int e = s_eid[r*MAXDEG + k];
                float val = s_als[s_src[e]*HEADS + h] + ald;
                val = (val > 0.f) ? val : NEG_SLOPE*val;
                s_alpha[e*HEADS + h] = expf(val - m) * inv;
            }
        }
        __syncthreads();

        // aggregate + mean heads + bias + gelu + residual (r is wave-uniform)
        float outv[TOK/256];
        #pragma unroll
        for (int j = 0; j < TOK/256; ++j) {
            int i = t + j*256;
            int r = i >> 7;
            int f = i & (HID-1);
            float acc = 0.f;
            int d = s_deg[r];
            for (int k = 0; k < d; ++k) {
                int e = s_eid[r*MAXDEG + k];
                int s = s_src[e];
                #pragma unroll
                for (int h = 0; h < HEADS; ++h)
                    acc = fmaf(s_alpha[e*HEADS + h], s_xp[s*KO + h*HID + f], acc);
            }
            acc = acc * (1.0f/HEADS) + bg[l*HID + f];
            outv[j] = gelu_exact(acc) + s_nf[i];
        }
        __syncthreads();   // all residual reads done before overwrite
        #pragma unroll
        for (int j = 0; j < TOK/256; ++j) s_nf[t + j*256] = outv[j];
        __syncthreads();
    }

    // ---- write graph_features (first output) ----
    for (int i = t; i < R*HID; i += 256)
        gf_out[(size_t)tok*TOK + i] = s_nf[i];
}

extern "C" void kernel_launch(void* const* d_in, const int* in_sizes, int n_in,
                              void* d_out, int out_size, void* d_ws, size_t ws_size,
                              hipStream_t stream) {
    const float* x      = (const float*)d_in[0];
    const float* Wenc   = (const float*)d_in[1];
    const float* benc   = (const float*)d_in[2];
    const float* gamma_ = (const float*)d_in[3];
    const float* beta_  = (const float*)d_in[4];
    const float* Wg     = (const float*)d_in[5];
    const float* asrc   = (const float*)d_in[6];
    const float* adst   = (const float*)d_in[7];
    const float* bg     = (const float*)d_in[8];
    const int*   srce   = (const int*)d_in[9];
    const int*   dste   = (const int*)d_in[10];

    const int E  = in_sizes[9];
    const int BT = in_sizes[0] / (R*C);   // 16*800 = 12800

    float* gf = (float*)d_out;                      // (BT, R*HID)
    float* rf = gf + (size_t)BT * TOK;              // (BT, R, HID)

    fused_gnn_kernel<<<BT, 256, 0, stream>>>(x, Wenc, benc, gamma_, beta_,
                                             Wg, asrc, adst, bg, srce, dste,
                                             gf, rf, E);
}

// Round 2
// 588.709 us; speedup vs baseline: 2.0705x; 2.0705x over previous
//
#include <hip/hip_runtime.h>
#include <hip/hip_bf16.h>
#include <math.h>

#define R 10
#define C 6
#define HID 128
#define HEADS 4
#define NL 3
#define KO 512            // HEADS*HID
#define TOK 1280          // R*HID
#define NCAT 544          // padded GEMM N: 512 xp + 8 logit cols + pad
#define NT 33             // ceil(520/16) N-tiles
#define NUSE 520
#define XPS 524           // s_xp row stride (floats), 16B-aligned rows
#define NFS 136           // s_nfb row stride (bf16 elems), 272B rows -> 2-way-free banks
#define LN_EPS 1e-5f
#define NEG_SLOPE 0.2f
#define MAXE 40
#define MAXDEG 16

typedef __attribute__((ext_vector_type(8))) short short8;
typedef __attribute__((ext_vector_type(4))) float floatx4;

__device__ __forceinline__ float gelu_exact(float v) {
    return 0.5f * v * (1.0f + erff(v * 0.70710678118654752440f));
}
__device__ __forceinline__ short f2bf(float v) {
    __hip_bfloat16 b = __float2bfloat16(v);
    return __builtin_bit_cast(short, b);
}

// ---- prep: Wcat[l][n][k] bf16, n-major k-contiguous ----
// n in [0,512): W^T columns; n in [512,516): W@asrc_h folded; [516,520): W@adst_h; rest 0.
__global__ void prep_wcat(const float* __restrict__ Wg,
                          const float* __restrict__ asrc,
                          const float* __restrict__ adst,
                          short* __restrict__ Wcat)
{
    int idx = blockIdx.x * 256 + threadIdx.x;
    const int TOTAL = NL * NCAT * HID;
    if (idx >= TOTAL) return;
    int k = idx & (HID - 1);
    int n = (idx >> 7) % NCAT;
    int l = idx / (NCAT * HID);
    float v = 0.f;
    if (n < KO) {
        v = Wg[((size_t)l * HID + k) * KO + n];
    } else if (n < KO + 8) {
        int h = (n - KO) & 3;
        const float* a = ((n - KO) < 4 ? asrc : adst) + (l * HEADS + h) * HID;
        const float* w = Wg + ((size_t)l * HID + k) * KO + h * HID;
        float s = 0.f;
        for (int f = 0; f < HID; ++f) s = fmaf(w[f], a[f], s);
        v = s;
    }
    Wcat[idx] = f2bf(v);
}

__global__ __launch_bounds__(256, 3) void fused_gnn_mfma(
    const float* __restrict__ x,      // (BT, 60)
    const float* __restrict__ Wenc,   // (R, C, HID)
    const float* __restrict__ benc,   // (R, HID)
    const float* __restrict__ gamma_, // (R, HID)
    const float* __restrict__ beta_,  // (R, HID)
    const short* __restrict__ Wcat,   // (NL, NCAT, HID) bf16
    const float* __restrict__ bg,     // (NL, HID)
    const int* __restrict__ srce, const int* __restrict__ dste,
    float* __restrict__ gf_out, float* __restrict__ rf_out, int E)
{
    __shared__ __align__(16) float s_xp[2 * R * XPS];   // 41.9 KB: xp + logit cols (fp32)
    __shared__ __align__(16) short s_nfb[2 * 16 * NFS]; // 8.7 KB: nf in bf16 MFMA-A layout
    __shared__ float s_un[320];                         // union: enc {xr[120],mu[20]@128,rs[20]@148} | alpha[2][40][4]
    __shared__ int s_src[MAXE], s_dst[MAXE];
    __shared__ int s_eid[R * MAXDEG], s_deg[R];

    const int t = threadIdx.x;
    const int lane = t & 63;
    const int wave = t >> 6;
    const int tok0 = blockIdx.x * 2;

    // ---- stage edges + x (both tokens contiguous: 120 floats) ----
    if (t < E) { s_src[t] = srce[t]; s_dst[t] = dste[t]; }
    if (t < 120) s_un[t] = x[(size_t)tok0 * 60 + t];
    __syncthreads();
    if (t < R) {
        int d = 0;
        for (int e = 0; e < E; ++e)
            if (s_dst[e] == t && d < MAXDEG) s_eid[t * MAXDEG + (d++)] = e;
        s_deg[t] = d;
    }

    // ---- encoder: h = x @ Wenc + benc, per-quad mapping q=(tk,r,f4) ----
    for (int q = t; q < 640; q += 256) {
        int tk = q >= 320; int qq = q - tk * 320;
        int r = qq >> 5; int f4 = (qq & 31) << 2;
        const float* xr = &s_un[tk * 60 + r * 6];
        float4 acc = *(const float4*)&benc[r * HID + f4];
        #pragma unroll
        for (int c = 0; c < 6; ++c) {
            float xv = xr[c];
            float4 wv = *(const float4*)&Wenc[(r * 6 + c) * HID + f4];
            acc.x = fmaf(xv, wv.x, acc.x);
            acc.y = fmaf(xv, wv.y, acc.y);
            acc.z = fmaf(xv, wv.z, acc.z);
            acc.w = fmaf(xv, wv.w, acc.w);
        }
        *(float4*)&s_xp[(tk * R + r) * XPS + f4] = acc;
    }
    __syncthreads();

    // ---- LayerNorm stats: one wave per row ----
    for (int rr = wave; rr < 20; rr += 4) {
        const float* row = &s_xp[rr * XPS];
        float v0 = row[lane], v1 = row[lane + 64];
        float sum = v0 + v1, sq = v0 * v0 + v1 * v1;
        #pragma unroll
        for (int off = 32; off > 0; off >>= 1) {
            sum += __shfl_down(sum, off);
            sq  += __shfl_down(sq,  off);
        }
        if (lane == 0) {
            float mu = sum * (1.0f / HID);
            float var = sq * (1.0f / HID) - mu * mu;
            s_un[128 + rr] = mu;
            s_un[148 + rr] = rsqrtf(var + LN_EPS);
        }
    }
    __syncthreads();

    // ---- normalize + affine + gelu -> nf_reg (residual), s_nfb (bf16 A), rf_out ----
    float4 nf_reg[3];
    {
        int nq = 0;
        for (int q = t; q < 640; q += 256, ++nq) {
            int tk = q >= 320; int qq = q - tk * 320;
            int r = qq >> 5; int f4 = (qq & 31) << 2;
            float4 v = *(const float4*)&s_xp[(tk * R + r) * XPS + f4];
            float mu = s_un[128 + tk * 10 + r];
            float rs = s_un[148 + tk * 10 + r];
            float4 g = *(const float4*)&gamma_[r * HID + f4];
            float4 b = *(const float4*)&beta_[r * HID + f4];
            float4 o;
            o.x = gelu_exact((v.x - mu) * rs * g.x + b.x);
            o.y = gelu_exact((v.y - mu) * rs * g.y + b.y);
            o.z = gelu_exact((v.z - mu) * rs * g.z + b.z);
            o.w = gelu_exact((v.w - mu) * rs * g.w + b.w);
            nf_reg[nq] = o;
            short4 pk; pk.x = f2bf(o.x); pk.y = f2bf(o.y); pk.z = f2bf(o.z); pk.w = f2bf(o.w);
            *(short4*)&s_nfb[(tk * 16 + r) * NFS + f4] = pk;
            *(float4*)&rf_out[(size_t)(tok0 + tk) * TOK + qq * 4] = o;
        }
    }
    __syncthreads();

    // ---- 3 GAT layers ----
    const int col = lane & 15;
    const int quad = lane >> 4;
    const int aoff = quad * 8;

    for (int l = 0; l < NL; ++l) {
        const short* __restrict__ Wl = Wcat + (size_t)l * NCAT * HID;

        // A fragments: rows m=lane&15, k=quad*8+j (+32 per kstep); reused across all N-tiles
        short8 aF[2][4];
        #pragma unroll
        for (int tk = 0; tk < 2; ++tk)
            #pragma unroll
            for (int ks = 0; ks < 4; ++ks)
                aF[tk][ks] = *(const short8*)&s_nfb[(tk * 16 + col) * NFS + ks * 32 + aoff];

        // GEMM: N-tiles round-robin over waves; B frags straight from L2 (bf16, coalesced)
        for (int nt = wave; nt < NT; nt += 4) {
            const short* Bp = Wl + (nt * 16 + col) * HID + aoff;
            short8 b0 = *(const short8*)(Bp);
            short8 b1 = *(const short8*)(Bp + 32);
            short8 b2 = *(const short8*)(Bp + 64);
            short8 b3 = *(const short8*)(Bp + 96);
            int n = nt * 16 + col;
            #pragma unroll
            for (int tk = 0; tk < 2; ++tk) {
                floatx4 c = {0.f, 0.f, 0.f, 0.f};
                c = __builtin_amdgcn_mfma_f32_16x16x32_bf16(aF[tk][0], b0, c, 0, 0, 0);
                c = __builtin_amdgcn_mfma_f32_16x16x32_bf16(aF[tk][1], b1, c, 0, 0, 0);
                c = __builtin_amdgcn_mfma_f32_16x16x32_bf16(aF[tk][2], b2, c, 0, 0, 0);
                c = __builtin_amdgcn_mfma_f32_16x16x32_bf16(aF[tk][3], b3, c, 0, 0, 0);
                if (n < NUSE) {
                    #pragma unroll
                    for (int j = 0; j < 4; ++j) {
                        int m = quad * 4 + j;          // C row = region
                        if (m < R) s_xp[(tk * R + m) * XPS + n] = c[j];
                    }
                }
            }
        }
        __syncthreads();

        // ---- segment softmax per (token, dst node, head): 80 threads ----
        if (t < 80) {
            int tk = t / 40; int rem = t - tk * 40;
            int r = rem >> 2; int h = rem & 3;
            const float* xb = &s_xp[tk * R * XPS];
            float ald = xb[r * XPS + 516 + h];
            int d = s_deg[r];
            float m = -1e30f;
            for (int k = 0; k < d; ++k) {
                int e = s_eid[r * MAXDEG + k];
                float val = xb[s_src[e] * XPS + 512 + h] + ald;
                val = (val > 0.f) ? val : NEG_SLOPE * val;
                m = fmaxf(m, val);
            }
            float ssum = 0.f;
            for (int k = 0; k < d; ++k) {
                int e = s_eid[r * MAXDEG + k];
                float val = xb[s_src[e] * XPS + 512 + h] + ald;
                val = (val > 0.f) ? val : NEG_SLOPE * val;
                ssum += expf(val - m);
            }
            float inv = 1.0f / ssum;
            for (int k = 0; k < d; ++k) {
                int e = s_eid[r * MAXDEG + k];
                float val = xb[s_src[e] * XPS + 512 + h] + ald;
                val = (val > 0.f) ? val : NEG_SLOPE * val;
                s_un[(tk * 40 + e) * 4 + h] = expf(val - m) * inv;
            }
        }
        __syncthreads();

        // ---- aggregate + mean heads + bias + gelu + residual ----
        {
            int nq = 0;
            for (int q = t; q < 640; q += 256, ++nq) {
                int tk = q >= 320; int qq = q - tk * 320;
                int r = qq >> 5; int f4 = (qq & 31) << 2;
                float4 acc = {0.f, 0.f, 0.f, 0.f};
                int d = s_deg[r];
                const float* xb = &s_xp[tk * R * XPS];
                for (int k = 0; k < d; ++k) {
                    int e = s_eid[r * MAXDEG + k];
                    const float* row = xb + s_src[e] * XPS;
                    #pragma unroll
                    for (int h = 0; h < 4; ++h) {
                        float a = s_un[(tk * 40 + e) * 4 + h];
                        float4 xv = *(const float4*)&row[h * HID + f4];
                        acc.x = fmaf(a, xv.x, acc.x);
                        acc.y = fmaf(a, xv.y, acc.y);
                        acc.z = fmaf(a, xv.z, acc.z);
                        acc.w = fmaf(a, xv.w, acc.w);
                    }
                }
                float4 bb = *(const float4*)&bg[l * HID + f4];
                float4 o;
                o.x = gelu_exact(acc.x * 0.25f + bb.x) + nf_reg[nq].x;
                o.y = gelu_exact(acc.y * 0.25f + bb.y) + nf_reg[nq].y;
                o.z = gelu_exact(acc.z * 0.25f + bb.z) + nf_reg[nq].z;
                o.w = gelu_exact(acc.w * 0.25f + bb.w) + nf_reg[nq].w;
                nf_reg[nq] = o;
                if (l < NL - 1) {
                    short4 pk; pk.x = f2bf(o.x); pk.y = f2bf(o.y); pk.z = f2bf(o.z); pk.w = f2bf(o.w);
                    *(short4*)&s_nfb[(tk * 16 + r) * NFS + f4] = pk;
                }
            }
        }
        __syncthreads();
    }

    // ---- write graph_features ----
    {
        int nq = 0;
        for (int q = t; q < 640; q += 256, ++nq) {
            int tk = q >= 320; int qq = q - tk * 320;
            *(float4*)&gf_out[(size_t)(tok0 + tk) * TOK + qq * 4] = nf_reg[nq];
        }
    }
}

extern "C" void kernel_launch(void* const* d_in, const int* in_sizes, int n_in,
                              void* d_out, int out_size, void* d_ws, size_t ws_size,
                              hipStream_t stream) {
    const float* x      = (const float*)d_in[0];
    const float* Wenc   = (const float*)d_in[1];
    const float* benc   = (const float*)d_in[2];
    const float* gamma_ = (const float*)d_in[3];
    const float* beta_  = (const float*)d_in[4];
    const float* Wg     = (const float*)d_in[5];
    const float* asrc   = (const float*)d_in[6];
    const float* adst   = (const float*)d_in[7];
    const float* bg     = (const float*)d_in[8];
    const int*   srce   = (const int*)d_in[9];
    const int*   dste   = (const int*)d_in[10];

    const int E  = in_sizes[9];
    const int BT = in_sizes[0] / (R * C);   // 12800

    float* gf = (float*)d_out;
    float* rf = gf + (size_t)BT * TOK;
    short* Wcat = (short*)d_ws;             // NL*NCAT*HID bf16 = 816 KB

    const int prep_total = NL * NCAT * HID;
    prep_wcat<<<(prep_total + 255) / 256, 256, 0, stream>>>(Wg, asrc, adst, Wcat);
    fused_gnn_mfma<<<BT / 2, 256, 0, stream>>>(x, Wenc, benc, gamma_, beta_,
                                               Wcat, bg, srce, dste, gf, rf, E);
}